// Round 26
// baseline (62.712 us; speedup 1.0000x reference)
//
#include <hip/hip_runtime.h>

namespace {

constexpr int B = 4, S = 4096, H = 16, D = 32;
constexpr int L = 32;             // chunk length
constexpr int NC = S / L;         // 128 chunks per sequence
constexpr int NBH = B * H;        // 64
constexpr int RS = H * D;         // 512 floats between consecutive time steps
constexpr float GEPS = 1.52587890625e-05f;  // 2^-16 per-step decay clamp

// Lore (rounds 6-25, measured):
//  - launch_bounds(256,w) caps VGPR ~256/w; cap < live set => GB-scale spill.
//  - k1 is the FIRST toucher of K/V/G each iteration (~half cold, r21
//    FETCH=49MB) and every 1-chunk-per-wave variant is latency-bound at
//    ~33-46us: one serial cumsum chain + only ~12KB loads in flight/wave.
//    Fix = more chunks per wave (MLP), not occupancy/barrier knobs.
//  - Wave-independent barrier-free kernels (shfl cross-lane, wave-private
//    LDS) beat block-cooperative ones (r23-25).
//  - NEVER quantize l below f32 (r21 absmax 1.5); scales/W in bf16 are fine.
//  - MFMA operand convention (HW-verified r12, absmax 0.5):
//    A-op: row = lane&31, k = 8*(lane>>5)+e (+16 for 2nd MFMA)
//    B-op: col = lane&31, same k
//    C/D : col = lane&31, row = (reg&3)+8*(reg>>2)+4*(lane>>5)

typedef __attribute__((ext_vector_type(8)))  short short8v;   // 8 bf16 = 4 VGPR
typedef __attribute__((ext_vector_type(16))) float f32x16;    // 16 f32 acc

__device__ __forceinline__ float flog2(float x) { return __builtin_amdgcn_logf(x); }
__device__ __forceinline__ float fexp2(float x) { return __builtin_amdgcn_exp2f(x); }
__device__ __forceinline__ unsigned f2bfu(float f) {          // fp32 -> bf16 (RNE)
    unsigned u = __float_as_uint(f);
    return (u + 0x7FFFu + ((u >> 16) & 1u)) >> 16;
}
__device__ __forceinline__ short f2bf(float f) { return (short)f2bfu(f); }
__device__ __forceinline__ float bf2f(short s) {              // bf16 -> fp32
    return __uint_as_float(((unsigned)(ushort)s) << 16);
}

// ---------------- Kernel 1: 2-chunk-per-wave barrier-free producer ------------
// 1024 blocks x 4 waves x 2 chunks. Zero LDS, zero barriers. All loads for
// BOTH chunks are independent -> ~24KB memory-level parallelism per wave.
__global__ __launch_bounds__(256)
void k1_wave2(const float* __restrict__ Kp, const float* __restrict__ Vp,
              const float* __restrict__ Gp, ushort* __restrict__ ChKV,
              float* __restrict__ ChG)
{
    const int tid = threadIdx.x;
    const int wv = tid >> 6;
    const int lane = tid & 63;
    const int half = lane >> 5;
    const int m = lane & 31;
    const int wid = blockIdx.x * 4 + wv;          // 4096 waves x 2 chunks

    const int chunk0 = wid * 2;
    long bases[2];
    #pragma unroll
    for (int z = 0; z < 2; ++z) {
        const int chunk = chunk0 + z;
        const int bh = chunk >> 7;
        const int c = chunk & (NC - 1);
        const int b = bh >> 4;
        const int h = bh & (H - 1);
        bases[z] = ((long)b * S + (long)c * L) * RS + h * D;
    }

    // ---- issue ALL independent loads for both chunks ----
    float graw0[16], graw1[16];
    float kraw0a[8], kraw0b[8], kraw1a[8], kraw1b[8];
    float vraw0[16], vraw1[16];
    {
        const float* g0 = Gp + bases[0] + (long)(half * 16) * RS + m;
        const float* g1 = Gp + bases[1] + (long)(half * 16) * RS + m;
        const float* k0 = Kp + bases[0] + m;
        const float* k1p = Kp + bases[1] + m;
        const float* v0 = Vp + bases[0] + (long)(half * 16) * RS + m;
        const float* v1 = Vp + bases[1] + (long)(half * 16) * RS + m;
        #pragma unroll
        for (int t = 0; t < 16; ++t) graw0[t] = g0[(long)t * RS];
        #pragma unroll
        for (int t = 0; t < 16; ++t) graw1[t] = g1[(long)t * RS];
        #pragma unroll
        for (int e = 0; e < 8; ++e) {
            kraw0a[e] = k0[(long)(8 * half + e) * RS];
            kraw0b[e] = k0[(long)(16 + 8 * half + e) * RS];
            kraw1a[e] = k1p[(long)(8 * half + e) * RS];
            kraw1b[e] = k1p[(long)(16 + 8 * half + e) * RS];
        }
        #pragma unroll
        for (int t = 0; t < 16; ++t) vraw0[t] = v0[(long)t * RS];
        #pragma unroll
        for (int t = 0; t < 16; ++t) vraw1[t] = v1[(long)t * RS];
    }

    // ---- per-chunk compute (z = 0, 1) ----
    #pragma unroll
    for (int z = 0; z < 2; ++z) {
        const int chunk = chunk0 + z;
        const float* graw = z ? graw1 : graw0;
        const float* vraw = z ? vraw1 : vraw0;
        const float* kra  = z ? kraw1a : kraw0a;
        const float* krb  = z ? kraw1b : kraw0b;

        // cumsum of log2(gate) down own half-column; cross-half via shfl
        float cum[16];
        {
            float run = 0.f;
            #pragma unroll
            for (int t = 0; t < 16; ++t) {
                run += flog2(fmaxf(graw[t], GEPS));
                cum[t] = run;
            }
        }
        {
            const float oth = __shfl_xor(cum[15], 32);
            if (half) {
                #pragma unroll
                for (int t = 0; t < 16; ++t) cum[t] += oth;
            }
        }
        const float c15 = cum[15];
        const float o15 = __shfl_xor(c15, 32);
        const float total = half ? c15 : o15;

        // W = v * 2^{total - l}, packed bf16 pairs
        unsigned wpk[8];
        #pragma unroll
        for (int j = 0; j < 8; ++j) {
            const float w0 = vraw[2 * j]     * fexp2(total - cum[2 * j]);
            const float w1 = vraw[2 * j + 1] * fexp2(total - cum[2 * j + 1]);
            wpk[j] = f2bfu(w0) | (f2bfu(w1) << 16);
        }
        // half-exchange -> B-fragments
        short8v wf0, wf1;
        {
            unsigned xf[4], rc[4];
            #pragma unroll
            for (int j = 0; j < 4; ++j) xf[j] = half ? wpk[j] : wpk[4 + j];
            #pragma unroll
            for (int j = 0; j < 4; ++j) rc[j] = (unsigned)__shfl_xor((int)xf[j], 32);
            uint4 w0u, w1u;
            w0u.x = half ? rc[0] : wpk[0];  w0u.y = half ? rc[1] : wpk[1];
            w0u.z = half ? rc[2] : wpk[2];  w0u.w = half ? rc[3] : wpk[3];
            w1u.x = half ? wpk[4] : rc[0];  w1u.y = half ? wpk[5] : rc[1];
            w1u.z = half ? wpk[6] : rc[2];  w1u.w = half ? wpk[7] : rc[3];
            wf0 = *(short8v*)&w0u;
            wf1 = *(short8v*)&w1u;
        }

        // K A-fragments
        short8v ka0, ka1;
        #pragma unroll
        for (int e = 0; e < 8; ++e) {
            ka0[e] = f2bf(kra[e]);
            ka1[e] = f2bf(krb[e]);
        }

        // ChKV[d][m] = sum_j K[j][d] * W[j][m]
        f32x16 acc;
        #pragma unroll
        for (int e = 0; e < 16; ++e) acc[e] = 0.f;
        acc = __builtin_amdgcn_mfma_f32_32x32x16_bf16(ka0, wf0, acc, 0, 0, 0);
        acc = __builtin_amdgcn_mfma_f32_32x32x16_bf16(ka1, wf1, acc, 0, 0, 0);

        ushort* kvout = ChKV + (long)chunk * (D * D);
        #pragma unroll
        for (int reg = 0; reg < 16; ++reg) {
            const int d = (reg & 3) + 8 * (reg >> 2) + 4 * half;
            kvout[d * D + m] = (ushort)f2bf(acc[reg]);
        }
        if (half) ChG[(long)chunk * D + m] = fexp2(c15);
    }
}

// ---------------- Kernel 2: inter-chunk scan (bf16 in/out, f32 state) --------
__global__ __launch_bounds__(256)
void k2_scan(ushort* __restrict__ ChKV, const float* __restrict__ ChG)
{
    const int bh = blockIdx.x >> 2;
    const int dg = blockIdx.x & 3;
    const int tid = threadIdx.x;
    const int d = dg * 8 + (tid >> 5);
    const int m = tid & 31;

    const long kvoff = (long)bh * NC * (D * D) + d * D + m;
    const long goff = (long)bh * NC * D + m;

    ushort ka[8]; float ga[8];
    #pragma unroll
    for (int t = 0; t < 8; ++t) {
        ka[t] = ChKV[kvoff + (long)t * (D * D)];
        ga[t] = ChG[goff + (long)t * D];
    }
    float st = 0.f;
    for (int c0 = 0; c0 < NC; c0 += 8) {
        ushort kb[8]; float gb2[8];
        const bool more = (c0 + 8) < NC;
        #pragma unroll
        for (int t = 0; t < 8; ++t) {
            kb[t]  = more ? ChKV[kvoff + (long)(c0 + 8 + t) * (D * D)] : (ushort)0;
            gb2[t] = more ? ChG[goff + (long)(c0 + 8 + t) * D] : 0.f;
        }
        #pragma unroll
        for (int t = 0; t < 8; ++t) {
            ChKV[kvoff + (long)(c0 + t) * (D * D)] = (ushort)f2bf(st); // START
            st = ga[t] * st + bf2f((short)ka[t]);
        }
        #pragma unroll
        for (int t = 0; t < 8; ++t) { ka[t] = kb[t]; ga[t] = gb2[t]; }
    }
}

// ---------------- Kernel 3: barrier-free wave-independent consumer ------------
// 1024 blocks x 4 waves x 2 sequential chunks (r23-25 verified).
__global__ __launch_bounds__(256)
void k3_seq(const float* __restrict__ Qp, const float* __restrict__ Kp,
            const float* __restrict__ Vp, const float* __restrict__ Gp,
            const ushort* __restrict__ S0b, float* __restrict__ Op)
{
    __shared__ __align__(16) ushort a_s[4][L][40];   // masked Gram, wave-private

    const int tid = threadIdx.x;
    const int wv = tid >> 6;
    const int lane = tid & 63;
    const int half = lane >> 5;
    const int m = lane & 31;
    const int wid = blockIdx.x * 4 + wv;             // 4096 waves

    for (int cc = 0; cc < 2; ++cc) {
        const int chunk = wid * 2 + cc;
        const int bh = chunk >> 7;
        const int c = chunk & (NC - 1);
        const int b = bh >> 4;
        const int h = bh & (H - 1);
        const long base = ((long)b * S + (long)c * L) * RS + h * D;
        const ushort* S0c = S0b + (long)chunk * (D * D);

        // Q/K fragments (row-major b128)
        const float* qrow = Qp + base + (long)m * RS + 8 * half;
        const float* krow = Kp + base + (long)m * RS + 8 * half;
        float4 qv0 = *(const float4*)(qrow);
        float4 qv1 = *(const float4*)(qrow + 4);
        float4 qv2 = *(const float4*)(qrow + 16);
        float4 qv3 = *(const float4*)(qrow + 20);
        float4 kv0 = *(const float4*)(krow);
        float4 kv1 = *(const float4*)(krow + 4);
        float4 kv2 = *(const float4*)(krow + 16);
        float4 kv3 = *(const float4*)(krow + 20);
        short8v qa0, qa1, ka0, ka1;
        {
            float qf[16] = {qv0.x,qv0.y,qv0.z,qv0.w, qv1.x,qv1.y,qv1.z,qv1.w,
                            qv2.x,qv2.y,qv2.z,qv2.w, qv3.x,qv3.y,qv3.z,qv3.w};
            float kf[16] = {kv0.x,kv0.y,kv0.z,kv0.w, kv1.x,kv1.y,kv1.z,kv1.w,
                            kv2.x,kv2.y,kv2.z,kv2.w, kv3.x,kv3.y,kv3.z,kv3.w};
            #pragma unroll
            for (int e = 0; e < 8; ++e) {
                qa0[e] = f2bf(qf[e]);     qa1[e] = f2bf(qf[8 + e]);
                ka0[e] = f2bf(kf[e]);     ka1[e] = f2bf(kf[8 + e]);
            }
        }

        // per-lane register cumsum of own half-column; cross-half via shfl
        float cum[16];
        {
            const float* gcol = Gp + base + (long)(half * 16) * RS + m;
            float run = 0.f;
            #pragma unroll
            for (int t = 0; t < 16; ++t) {
                run += flog2(fmaxf(gcol[(long)t * RS], GEPS));
                cum[t] = run;
            }
        }
        {
            const float oth = __shfl_xor(cum[15], 32);
            if (half) {
                #pragma unroll
                for (int t = 0; t < 16; ++t) cum[t] += oth;
            }
        }
        const float c7 = cum[7], c15 = cum[15];
        const float o7 = __shfl_xor(c7, 32), o15 = __shfl_xor(c15, 32);
        float es4[4];
        es4[0] = half ? o7  : c7;
        es4[1] = half ? o15 : c15;
        es4[2] = half ? c7  : o7;
        es4[3] = half ? c15 : o15;

        // li at C-rows via 8 paired exchanges
        float li[16];
        #pragma unroll
        for (int j = 0; j < 8; ++j) {
            const int tl = (j & 3) + 8 * (j >> 2);     // 0..3, 8..11
            const float send = half ? cum[tl] : cum[tl + 4];
            const float recv = __shfl_xor(send, 32);
            li[j]     = half ? recv        : cum[tl];
            li[j + 8] = half ? cum[tl + 4] : recv;
        }

        // W (SUB-scaled) in registers + half-exchange -> B-fragments
        unsigned wpk[8];
        {
            const float* vcol = Vp + base + (long)(half * 16) * RS + m;
            #pragma unroll
            for (int j = 0; j < 8; ++j) {
                const int t0 = 2 * j, t1 = 2 * j + 1;
                const float e0 = (t0 < 8) ? c7 : c15;
                const float e1 = (t1 < 8) ? c7 : c15;
                const float w0 = vcol[(long)t0 * RS] * fexp2(e0 - cum[t0]);
                const float w1 = vcol[(long)t1 * RS] * fexp2(e1 - cum[t1]);
                wpk[j] = f2bfu(w0) | (f2bfu(w1) << 16);
            }
        }
        short8v wfk0, wfk1;
        {
            unsigned xf[4], rc[4];
            #pragma unroll
            for (int j = 0; j < 4; ++j) xf[j] = half ? wpk[j] : wpk[4 + j];
            #pragma unroll
            for (int j = 0; j < 4; ++j) rc[j] = (unsigned)__shfl_xor((int)xf[j], 32);
            uint4 w0u, w1u;
            w0u.x = half ? rc[0] : wpk[0];  w0u.y = half ? rc[1] : wpk[1];
            w0u.z = half ? rc[2] : wpk[2];  w0u.w = half ? rc[3] : wpk[3];
            w1u.x = half ? wpk[4] : rc[0];  w1u.y = half ? wpk[5] : rc[1];
            w1u.z = half ? wpk[6] : rc[2];  w1u.w = half ? wpk[7] : rc[3];
            wfk0 = *(short8v*)&w0u;
            wfk1 = *(short8v*)&w1u;
        }

        // Gram A = Q.K^T -> masked bf16 a_s (wave-private; no block barrier)
        {
            f32x16 acc;
            #pragma unroll
            for (int e = 0; e < 16; ++e) acc[e] = 0.f;
            acc = __builtin_amdgcn_mfma_f32_32x32x16_bf16(qa0, ka0, acc, 0, 0, 0);
            acc = __builtin_amdgcn_mfma_f32_32x32x16_bf16(qa1, ka1, acc, 0, 0, 0);
            #pragma unroll
            for (int reg = 0; reg < 16; ++reg) {
                const int irow = (reg & 3) + 8 * (reg >> 2) + 4 * half;
                const float av = (m <= irow) ? acc[reg] : 0.f;
                a_s[wv][irow][m] = (ushort)f2bf(av);
            }
        }

        // cross-chunk: 2^{l_i} * (Q.S0), S0 bf16 from global
        f32x16 sacc;
        #pragma unroll
        for (int e = 0; e < 16; ++e) sacc[e] = 0.f;
        {
            short8v sf0, sf1;
            #pragma unroll
            for (int e = 0; e < 8; ++e) {
                sf0[e] = (short)S0c[(8 * half + e) * D + m];
                sf1[e] = (short)S0c[(16 + 8 * half + e) * D + m];
            }
            sacc = __builtin_amdgcn_mfma_f32_32x32x16_bf16(qa0, sf0, sacc, 0, 0, 0);
            sacc = __builtin_amdgcn_mfma_f32_32x32x16_bf16(qa1, sf1, sacc, 0, 0, 0);
        }
        f32x16 out;
        #pragma unroll
        for (int reg = 0; reg < 16; ++reg) out[reg] = fexp2(li[reg]) * sacc[reg];

        // intra-chunk P (a_s read after same-wave write: program order)
        #pragma unroll
        for (int ks = 0; ks < 2; ++ks) {
            const short8v af = *(const short8v*)&a_s[wv][m][16 * ks + 8 * half];
            const short8v wf = ks ? wfk1 : wfk0;
            #pragma unroll
            for (int par = 0; par < 2; ++par) {
                const int s = 2 * ks + par;
                short8v am;
                #pragma unroll
                for (int e = 0; e < 8; ++e) am[e] = (half == par) ? af[e] : (short)0;
                f32x16 p;
                #pragma unroll
                for (int e = 0; e < 16; ++e) p[e] = 0.f;
                p = __builtin_amdgcn_mfma_f32_32x32x16_bf16(am, wf, p, 0, 0, 0);
                #pragma unroll
                for (int reg = 0; reg < 16; ++reg)
                    out[reg] += fexp2(fminf(li[reg] - es4[s], 120.f)) * p[reg];
            }
        }

        #pragma unroll
        for (int reg = 0; reg < 16; ++reg) {
            const int irow = (reg & 3) + 8 * (reg >> 2) + 4 * half;
            Op[base + (long)irow * RS + m] = out[reg];
        }
    }
}

} // namespace

extern "C" void kernel_launch(void* const* d_in, const int* in_sizes, int n_in,
                              void* d_out, int out_size, void* d_ws, size_t ws_size,
                              hipStream_t stream)
{
    const float* q = (const float*)d_in[0];
    const float* k = (const float*)d_in[1];
    const float* v = (const float*)d_in[2];
    const float* g = (const float*)d_in[3];
    float* out = (float*)d_out;

    ushort* ChKV = (ushort*)d_ws;                          // [8192][1024] bf16 (16.8 MB)
    float* ChG = (float*)(ChKV + (long)NBH * NC * D * D);  // [8192][32] f32   (1.05 MB)

    dim3 blk(256);
    k1_wave2<<<dim3(NBH * NC / 8), blk, 0, stream>>>(k, v, g, ChKV, ChG);
    k2_scan<<<dim3(NBH * 4), blk, 0, stream>>>(ChKV, ChG);
    k3_seq<<<dim3(NBH * NC / 8), blk, 0, stream>>>(q, k, v, g, ChKV, out);
}

// Round 27
// 62.632 us; speedup vs baseline: 1.0013x; 1.0013x over previous
//
#include <hip/hip_runtime.h>

namespace {

constexpr int B = 4, S = 4096, H = 16, D = 32;
constexpr int L = 32;             // chunk length
constexpr int NC = S / L;         // 128 chunks per sequence
constexpr int NBH = B * H;        // 64
constexpr int RS = H * D;         // 512 floats between consecutive time steps
constexpr float GEPS = 1.52587890625e-05f;  // 2^-16 per-step decay clamp

// Lore (rounds 6-26, measured):
//  - launch_bounds(256,w) caps VGPR ~256/w; cap < live set => GB-scale spill.
//  - The harness ws-poison fills (268MB @ 6.8TB/s) evict L3 between replays:
//    k1's K/V/G reads are PERMANENTLY cold (FETCH 49MB every iteration).
//  - r26: hoisting 96 scalar loads fails -- allocator keeps VGPR at 68 and
//    serializes (1.7TB/s). Fix = fewer/fatter loads: 12 independent b128
//    row loads/lane staged via wave-private LDS (no barriers), columns read
//    from LDS (unpadded [32][32] f32 col reads are bank-perfect).
//  - Wave-independent barrier-free kernels beat block-cooperative (r23-25).
//  - NEVER quantize l below f32 (r21 absmax 1.5); scales/W in bf16 are fine.
//  - MFMA operand convention (HW-verified r12, absmax 0.5):
//    A-op: row = lane&31, k = 8*(lane>>5)+e (+16 for 2nd MFMA)
//    B-op: col = lane&31, same k
//    C/D : col = lane&31, row = (reg&3)+8*(reg>>2)+4*(lane>>5)

typedef __attribute__((ext_vector_type(8)))  short short8v;   // 8 bf16 = 4 VGPR
typedef __attribute__((ext_vector_type(16))) float f32x16;    // 16 f32 acc

__device__ __forceinline__ float flog2(float x) { return __builtin_amdgcn_logf(x); }
__device__ __forceinline__ float fexp2(float x) { return __builtin_amdgcn_exp2f(x); }
__device__ __forceinline__ unsigned f2bfu(float f) {          // fp32 -> bf16 (RNE)
    unsigned u = __float_as_uint(f);
    return (u + 0x7FFFu + ((u >> 16) & 1u)) >> 16;
}
__device__ __forceinline__ short f2bf(float f) { return (short)f2bfu(f); }
__device__ __forceinline__ float bf2f(short s) {              // bf16 -> fp32
    return __uint_as_float(((unsigned)(ushort)s) << 16);
}

// ---------------- Kernel 1: b128-staged wave-independent producer -------------
// 2048 blocks x 4 waves x 1 chunk. Per lane: 12 independent float4 row loads
// (K,V,G) -> wave-private LDS slot -> column consume. Zero barriers.
__global__ __launch_bounds__(256)
void k1_ldsb(const float* __restrict__ Kp, const float* __restrict__ Vp,
             const float* __restrict__ Gp, ushort* __restrict__ ChKV,
             float* __restrict__ ChG)
{
    __shared__ __align__(16) float stg[4][3][L][D];   // 48KB, wave-private slots

    const int tid = threadIdx.x;
    const int wv = tid >> 6;
    const int lane = tid & 63;
    const int half = lane >> 5;
    const int m = lane & 31;

    const int chunk = blockIdx.x * 4 + wv;
    const int bh = chunk >> 7;
    const int c = chunk & (NC - 1);
    const int b = bh >> 4;
    const int h = bh & (H - 1);
    const long base = ((long)b * S + (long)c * L) * RS + h * D;

    // ---- stage: 12 independent b128 row loads (coalesced 128B segments) ----
    const int srow = lane >> 3;           // 0..7
    const int scol = (lane & 7) * 4;      // 0,4,..,28
    float4 rK[4], rV[4], rG[4];
    {
        const long ro = base + (long)srow * RS + scol;
        #pragma unroll
        for (int gblk = 0; gblk < 4; ++gblk)
            rK[gblk] = *(const float4*)(Kp + ro + (long)(gblk * 8) * RS);
        #pragma unroll
        for (int gblk = 0; gblk < 4; ++gblk)
            rV[gblk] = *(const float4*)(Vp + ro + (long)(gblk * 8) * RS);
        #pragma unroll
        for (int gblk = 0; gblk < 4; ++gblk)
            rG[gblk] = *(const float4*)(Gp + ro + (long)(gblk * 8) * RS);
    }
    #pragma unroll
    for (int gblk = 0; gblk < 4; ++gblk) {
        *(float4*)&stg[wv][0][gblk * 8 + srow][scol] = rK[gblk];
        *(float4*)&stg[wv][1][gblk * 8 + srow][scol] = rV[gblk];
        *(float4*)&stg[wv][2][gblk * 8 + srow][scol] = rG[gblk];
    }
    // same-wave ds ordering: compiler inserts lgkmcnt before dependent reads

    // ---- cumsum of log2(gate) down own half-column; cross-half via shfl ----
    float cum[16];
    {
        float run = 0.f;
        #pragma unroll
        for (int t = 0; t < 16; ++t) {
            run += flog2(fmaxf(stg[wv][2][half * 16 + t][m], GEPS));
            cum[t] = run;
        }
    }
    {
        const float oth = __shfl_xor(cum[15], 32);
        if (half) {
            #pragma unroll
            for (int t = 0; t < 16; ++t) cum[t] += oth;
        }
    }
    const float c15 = cum[15];
    const float o15 = __shfl_xor(c15, 32);
    const float total = half ? c15 : o15;

    // ---- W = v * 2^{total - l}, packed bf16 pairs ----
    unsigned wpk[8];
    #pragma unroll
    for (int j = 0; j < 8; ++j) {
        const float w0 = stg[wv][1][half * 16 + 2 * j][m]     * fexp2(total - cum[2 * j]);
        const float w1 = stg[wv][1][half * 16 + 2 * j + 1][m] * fexp2(total - cum[2 * j + 1]);
        wpk[j] = f2bfu(w0) | (f2bfu(w1) << 16);
    }
    // half-exchange -> B-fragments (r19-verified)
    short8v wf0, wf1;
    {
        unsigned xf[4], rc[4];
        #pragma unroll
        for (int j = 0; j < 4; ++j) xf[j] = half ? wpk[j] : wpk[4 + j];
        #pragma unroll
        for (int j = 0; j < 4; ++j) rc[j] = (unsigned)__shfl_xor((int)xf[j], 32);
        uint4 w0u, w1u;
        w0u.x = half ? rc[0] : wpk[0];  w0u.y = half ? rc[1] : wpk[1];
        w0u.z = half ? rc[2] : wpk[2];  w0u.w = half ? rc[3] : wpk[3];
        w1u.x = half ? wpk[4] : rc[0];  w1u.y = half ? wpk[5] : rc[1];
        w1u.z = half ? wpk[6] : rc[2];  w1u.w = half ? wpk[7] : rc[3];
        wf0 = *(short8v*)&w0u;
        wf1 = *(short8v*)&w1u;
    }

    // ---- K A-fragments from LDS columns ----
    short8v ka0, ka1;
    #pragma unroll
    for (int e = 0; e < 8; ++e) {
        ka0[e] = f2bf(stg[wv][0][8 * half + e][m]);
        ka1[e] = f2bf(stg[wv][0][16 + 8 * half + e][m]);
    }

    // ---- ChKV[d][m] = sum_j K[j][d] * W[j][m]  (2 MFMAs) ----
    f32x16 acc;
    #pragma unroll
    for (int e = 0; e < 16; ++e) acc[e] = 0.f;
    acc = __builtin_amdgcn_mfma_f32_32x32x16_bf16(ka0, wf0, acc, 0, 0, 0);
    acc = __builtin_amdgcn_mfma_f32_32x32x16_bf16(ka1, wf1, acc, 0, 0, 0);

    ushort* kvout = ChKV + (long)chunk * (D * D);
    #pragma unroll
    for (int reg = 0; reg < 16; ++reg) {
        const int d = (reg & 3) + 8 * (reg >> 2) + 4 * half;
        kvout[d * D + m] = (ushort)f2bf(acc[reg]);
    }
    if (half) ChG[(long)chunk * D + m] = fexp2(c15);
}

// ---------------- Kernel 2: inter-chunk scan (bf16 in/out, f32 state) --------
__global__ __launch_bounds__(256)
void k2_scan(ushort* __restrict__ ChKV, const float* __restrict__ ChG)
{
    const int bh = blockIdx.x >> 2;
    const int dg = blockIdx.x & 3;
    const int tid = threadIdx.x;
    const int d = dg * 8 + (tid >> 5);
    const int m = tid & 31;

    const long kvoff = (long)bh * NC * (D * D) + d * D + m;
    const long goff = (long)bh * NC * D + m;

    ushort ka[8]; float ga[8];
    #pragma unroll
    for (int t = 0; t < 8; ++t) {
        ka[t] = ChKV[kvoff + (long)t * (D * D)];
        ga[t] = ChG[goff + (long)t * D];
    }
    float st = 0.f;
    for (int c0 = 0; c0 < NC; c0 += 8) {
        ushort kb[8]; float gb2[8];
        const bool more = (c0 + 8) < NC;
        #pragma unroll
        for (int t = 0; t < 8; ++t) {
            kb[t]  = more ? ChKV[kvoff + (long)(c0 + 8 + t) * (D * D)] : (ushort)0;
            gb2[t] = more ? ChG[goff + (long)(c0 + 8 + t) * D] : 0.f;
        }
        #pragma unroll
        for (int t = 0; t < 8; ++t) {
            ChKV[kvoff + (long)(c0 + t) * (D * D)] = (ushort)f2bf(st); // START
            st = ga[t] * st + bf2f((short)ka[t]);
        }
        #pragma unroll
        for (int t = 0; t < 8; ++t) { ka[t] = kb[t]; ga[t] = gb2[t]; }
    }
}

// ---------------- Kernel 3: barrier-free wave-independent consumer ------------
// 1024 blocks x 4 waves x 2 sequential chunks (r23-26 verified).
__global__ __launch_bounds__(256)
void k3_seq(const float* __restrict__ Qp, const float* __restrict__ Kp,
            const float* __restrict__ Vp, const float* __restrict__ Gp,
            const ushort* __restrict__ S0b, float* __restrict__ Op)
{
    __shared__ __align__(16) ushort a_s[4][L][40];   // masked Gram, wave-private

    const int tid = threadIdx.x;
    const int wv = tid >> 6;
    const int lane = tid & 63;
    const int half = lane >> 5;
    const int m = lane & 31;
    const int wid = blockIdx.x * 4 + wv;             // 4096 waves

    for (int cc = 0; cc < 2; ++cc) {
        const int chunk = wid * 2 + cc;
        const int bh = chunk >> 7;
        const int c = chunk & (NC - 1);
        const int b = bh >> 4;
        const int h = bh & (H - 1);
        const long base = ((long)b * S + (long)c * L) * RS + h * D;
        const ushort* S0c = S0b + (long)chunk * (D * D);

        // Q/K fragments (row-major b128)
        const float* qrow = Qp + base + (long)m * RS + 8 * half;
        const float* krow = Kp + base + (long)m * RS + 8 * half;
        float4 qv0 = *(const float4*)(qrow);
        float4 qv1 = *(const float4*)(qrow + 4);
        float4 qv2 = *(const float4*)(qrow + 16);
        float4 qv3 = *(const float4*)(qrow + 20);
        float4 kv0 = *(const float4*)(krow);
        float4 kv1 = *(const float4*)(krow + 4);
        float4 kv2 = *(const float4*)(krow + 16);
        float4 kv3 = *(const float4*)(krow + 20);
        short8v qa0, qa1, ka0, ka1;
        {
            float qf[16] = {qv0.x,qv0.y,qv0.z,qv0.w, qv1.x,qv1.y,qv1.z,qv1.w,
                            qv2.x,qv2.y,qv2.z,qv2.w, qv3.x,qv3.y,qv3.z,qv3.w};
            float kf[16] = {kv0.x,kv0.y,kv0.z,kv0.w, kv1.x,kv1.y,kv1.z,kv1.w,
                            kv2.x,kv2.y,kv2.z,kv2.w, kv3.x,kv3.y,kv3.z,kv3.w};
            #pragma unroll
            for (int e = 0; e < 8; ++e) {
                qa0[e] = f2bf(qf[e]);     qa1[e] = f2bf(qf[8 + e]);
                ka0[e] = f2bf(kf[e]);     ka1[e] = f2bf(kf[8 + e]);
            }
        }

        // per-lane register cumsum of own half-column; cross-half via shfl
        float cum[16];
        {
            const float* gcol = Gp + base + (long)(half * 16) * RS + m;
            float run = 0.f;
            #pragma unroll
            for (int t = 0; t < 16; ++t) {
                run += flog2(fmaxf(gcol[(long)t * RS], GEPS));
                cum[t] = run;
            }
        }
        {
            const float oth = __shfl_xor(cum[15], 32);
            if (half) {
                #pragma unroll
                for (int t = 0; t < 16; ++t) cum[t] += oth;
            }
        }
        const float c7 = cum[7], c15 = cum[15];
        const float o7 = __shfl_xor(c7, 32), o15 = __shfl_xor(c15, 32);
        float es4[4];
        es4[0] = half ? o7  : c7;
        es4[1] = half ? o15 : c15;
        es4[2] = half ? c7  : o7;
        es4[3] = half ? c15 : o15;

        // li at C-rows via 8 paired exchanges
        float li[16];
        #pragma unroll
        for (int j = 0; j < 8; ++j) {
            const int tl = (j & 3) + 8 * (j >> 2);     // 0..3, 8..11
            const float send = half ? cum[tl] : cum[tl + 4];
            const float recv = __shfl_xor(send, 32);
            li[j]     = half ? recv        : cum[tl];
            li[j + 8] = half ? cum[tl + 4] : recv;
        }

        // W (SUB-scaled) in registers + half-exchange -> B-fragments
        unsigned wpk[8];
        {
            const float* vcol = Vp + base + (long)(half * 16) * RS + m;
            #pragma unroll
            for (int j = 0; j < 8; ++j) {
                const int t0 = 2 * j, t1 = 2 * j + 1;
                const float e0 = (t0 < 8) ? c7 : c15;
                const float e1 = (t1 < 8) ? c7 : c15;
                const float w0 = vcol[(long)t0 * RS] * fexp2(e0 - cum[t0]);
                const float w1 = vcol[(long)t1 * RS] * fexp2(e1 - cum[t1]);
                wpk[j] = f2bfu(w0) | (f2bfu(w1) << 16);
            }
        }
        short8v wfk0, wfk1;
        {
            unsigned xf[4], rc[4];
            #pragma unroll
            for (int j = 0; j < 4; ++j) xf[j] = half ? wpk[j] : wpk[4 + j];
            #pragma unroll
            for (int j = 0; j < 4; ++j) rc[j] = (unsigned)__shfl_xor((int)xf[j], 32);
            uint4 w0u, w1u;
            w0u.x = half ? rc[0] : wpk[0];  w0u.y = half ? rc[1] : wpk[1];
            w0u.z = half ? rc[2] : wpk[2];  w0u.w = half ? rc[3] : wpk[3];
            w1u.x = half ? wpk[4] : rc[0];  w1u.y = half ? wpk[5] : rc[1];
            w1u.z = half ? wpk[6] : rc[2];  w1u.w = half ? wpk[7] : rc[3];
            wfk0 = *(short8v*)&w0u;
            wfk1 = *(short8v*)&w1u;
        }

        // Gram A = Q.K^T -> masked bf16 a_s (wave-private; no block barrier)
        {
            f32x16 acc;
            #pragma unroll
            for (int e = 0; e < 16; ++e) acc[e] = 0.f;
            acc = __builtin_amdgcn_mfma_f32_32x32x16_bf16(qa0, ka0, acc, 0, 0, 0);
            acc = __builtin_amdgcn_mfma_f32_32x32x16_bf16(qa1, ka1, acc, 0, 0, 0);
            #pragma unroll
            for (int reg = 0; reg < 16; ++reg) {
                const int irow = (reg & 3) + 8 * (reg >> 2) + 4 * half;
                const float av = (m <= irow) ? acc[reg] : 0.f;
                a_s[wv][irow][m] = (ushort)f2bf(av);
            }
        }

        // cross-chunk: 2^{l_i} * (Q.S0), S0 bf16 from global
        f32x16 sacc;
        #pragma unroll
        for (int e = 0; e < 16; ++e) sacc[e] = 0.f;
        {
            short8v sf0, sf1;
            #pragma unroll
            for (int e = 0; e < 8; ++e) {
                sf0[e] = (short)S0c[(8 * half + e) * D + m];
                sf1[e] = (short)S0c[(16 + 8 * half + e) * D + m];
            }
            sacc = __builtin_amdgcn_mfma_f32_32x32x16_bf16(qa0, sf0, sacc, 0, 0, 0);
            sacc = __builtin_amdgcn_mfma_f32_32x32x16_bf16(qa1, sf1, sacc, 0, 0, 0);
        }
        f32x16 out;
        #pragma unroll
        for (int reg = 0; reg < 16; ++reg) out[reg] = fexp2(li[reg]) * sacc[reg];

        // intra-chunk P (a_s read after same-wave write: program order)
        #pragma unroll
        for (int ks = 0; ks < 2; ++ks) {
            const short8v af = *(const short8v*)&a_s[wv][m][16 * ks + 8 * half];
            const short8v wf = ks ? wfk1 : wfk0;
            #pragma unroll
            for (int par = 0; par < 2; ++par) {
                const int s = 2 * ks + par;
                short8v am;
                #pragma unroll
                for (int e = 0; e < 8; ++e) am[e] = (half == par) ? af[e] : (short)0;
                f32x16 p;
                #pragma unroll
                for (int e = 0; e < 16; ++e) p[e] = 0.f;
                p = __builtin_amdgcn_mfma_f32_32x32x16_bf16(am, wf, p, 0, 0, 0);
                #pragma unroll
                for (int reg = 0; reg < 16; ++reg)
                    out[reg] += fexp2(fminf(li[reg] - es4[s], 120.f)) * p[reg];
            }
        }

        #pragma unroll
        for (int reg = 0; reg < 16; ++reg) {
            const int irow = (reg & 3) + 8 * (reg >> 2) + 4 * half;
            Op[base + (long)irow * RS + m] = out[reg];
        }
    }
}

} // namespace

extern "C" void kernel_launch(void* const* d_in, const int* in_sizes, int n_in,
                              void* d_out, int out_size, void* d_ws, size_t ws_size,
                              hipStream_t stream)
{
    const float* q = (const float*)d_in[0];
    const float* k = (const float*)d_in[1];
    const float* v = (const float*)d_in[2];
    const float* g = (const float*)d_in[3];
    float* out = (float*)d_out;

    ushort* ChKV = (ushort*)d_ws;                          // [8192][1024] bf16 (16.8 MB)
    float* ChG = (float*)(ChKV + (long)NBH * NC * D * D);  // [8192][32] f32   (1.05 MB)

    dim3 blk(256);
    k1_ldsb<<<dim3(NBH * NC / 4), blk, 0, stream>>>(k, v, g, ChKV, ChG);
    k2_scan<<<dim3(NBH * 4), blk, 0, stream>>>(ChKV, ChG);
    k3_seq<<<dim3(NBH * NC / 8), blk, 0, stream>>>(q, k, v, g, ChKV, out);
}